// Round 3
// baseline (76.316 us; speedup 1.0000x reference)
//
#include <hip/hip_runtime.h>
#include <math.h>

// QConv2d: x (32,4,64,64) f32, params (4,8,16,16) f32 -> out (32,32,32,32) f32
// B=32 C=4 H=W=64, KH=KW=2 stride 2 -> px=py=32, NW=4, DIM=16, D=8, M=32768

#define NMAT 32          // C*D matrices
#define TAYLOR_N 9

// ---------------- Kernel 1: W'[c*8+d][j][i] = expm(SH)[i][j] * (-i)^popc(i) ----
__global__ __launch_bounds__(256) void expm_kernel(const float* __restrict__ params,
                                                   float2* __restrict__ wp) {
    __shared__ float2 X[256];
    __shared__ float2 P0[256];
    __shared__ float2 P1[256];
    __shared__ float red[256];
    __shared__ float srow[16];
    __shared__ int ssexp;

    const int bid = blockIdx.x;      // c*8 + d
    const int tid = threadIdx.x;
    const int i = tid >> 4, j = tid & 15;

    const float* pm = params + bid * 256;
    float pij = pm[i * 16 + j];
    float pji = pm[j * 16 + i];
    float ar = pij - pji;   // asym -> real part of SH
    float ai = pij + pji;   // sym  -> imag part of SH
    red[tid] = fabsf(ar) + fabsf(ai);
    __syncthreads();
    if (j == 0) {
        float s = 0.f;
        for (int t = 0; t < 16; ++t) s += red[i * 16 + t];
        srow[i] = s;
    }
    __syncthreads();
    if (tid == 0) {
        float mx = 0.f;
        for (int t = 0; t < 16; ++t) mx = fmaxf(mx, srow[t]);
        int se = 0;
        while (mx > 0.5f && se < 40) { mx *= 0.5f; se++; }
        ssexp = se;
    }
    __syncthreads();
    const int sexp = ssexp;
    const float scale = exp2f((float)(-sexp));
    const float xr = ar * scale, xi = ai * scale;
    X[tid] = make_float2(xr, xi);
    // P = I + X/N
    float2 p = make_float2(xr / TAYLOR_N + ((i == j) ? 1.f : 0.f), xi / TAYLOR_N);
    P0[tid] = p;
    __syncthreads();

    float2* cur = P0;
    float2* nxt = P1;
    // Horner: P = I + X*P/k for k = N-1 .. 1
    for (int k = TAYLOR_N - 1; k >= 1; --k) {
        float accr = 0.f, acci = 0.f;
        #pragma unroll
        for (int t = 0; t < 16; ++t) {
            float2 a = X[i * 16 + t];
            float2 b = cur[t * 16 + j];
            accr += a.x * b.x - a.y * b.y;
            acci += a.x * b.y + a.y * b.x;
        }
        float inv = 1.f / (float)k;
        float2 np = make_float2(accr * inv + ((i == j) ? 1.f : 0.f), acci * inv);
        __syncthreads();
        nxt[tid] = np;
        __syncthreads();
        float2* tmp = cur; cur = nxt; nxt = tmp;
    }
    // squarings
    for (int sq = 0; sq < sexp; ++sq) {
        float accr = 0.f, acci = 0.f;
        #pragma unroll
        for (int t = 0; t < 16; ++t) {
            float2 a = cur[i * 16 + t];
            float2 b = cur[t * 16 + j];
            accr += a.x * b.x - a.y * b.y;
            acci += a.x * b.y + a.y * b.x;
        }
        __syncthreads();
        nxt[tid] = make_float2(accr, acci);
        __syncthreads();
        float2* tmp = cur; cur = nxt; nxt = tmp;
    }
    // E[i][j] = U[i][j]; store W'[j][i] = U[i][j]*(-i)^popc(i)
    float2 e = cur[tid];
    int pc = __popc(i) & 3;
    float2 o;
    if (pc == 0)      o = make_float2( e.x,  e.y);
    else if (pc == 1) o = make_float2( e.y, -e.x);
    else if (pc == 2) o = make_float2(-e.x, -e.y);
    else              o = make_float2(-e.y,  e.x);
    wp[(bid * 16 + j) * 16 + i] = o;
}

// Fast acos: A&S 4.4.45, |abs err| <= 6.8e-5 over [-1,1]
__device__ __forceinline__ float acos_fast(float t) {
    float ax = fabsf(t);
    float p = fmaf(ax, -0.0187293f, 0.0742610f);
    p = fmaf(ax, p, -0.2121144f);
    p = fmaf(ax, p, 1.5707288f);
    float f = sqrtf(1.0f - ax) * p;
    return (t >= 0.f) ? f : (3.14159265358979f - f);
}

// ---------------- Kernel 2: main compute ------------------------------------
// grid = 8(d) * 128(mb) blocks, 512 threads.
// Threads [0,256): channels {0,1}; threads [256,512): channels {2,3}.
// Half 1 deposits partials in LDS; half 0 adds and stores. No atomics/memset.
__global__ __launch_bounds__(512) void qconv_kernel(const float* __restrict__ x,
                                                    const float2* __restrict__ wp,
                                                    float* __restrict__ out) {
    __shared__ float lds[4][256];

    const int bidx = blockIdx.x;
    const int d = bidx >> 7;          // uniform per block
    const int mb = bidx & 127;
    const int tid = threadIdx.x;
    const int chalf = tid >> 8;       // wave-uniform (bit 8)
    const int tm = tid & 255;
    const int m = mb * 256 + tm;
    const int b = m >> 10;
    const int rem = m & 1023;
    const int ix = rem >> 5;
    const int iy = rem & 31;

    float outacc0 = 0.f, outacc1 = 0.f, outacc2 = 0.f, outacc3 = 0.f;

    #pragma unroll
    for (int cc = 0; cc < 2; ++cc) {
        const int c = chalf * 2 + cc;
        const float* xc = x + (((b << 2) + c) * 64 + 2 * ix) * 64 + 2 * iy;
        float2 p0 = *(const float2*)xc;          // theta0, theta1 (kh=0)
        float2 p1 = *(const float2*)(xc + 64);   // theta2, theta3 (kh=1)

        float sn0, cs0, sn1, cs1, sn2, cs2, sn3, cs3;
        __sincosf(p0.x * 0.5f, &sn0, &cs0);
        __sincosf(p0.y * 0.5f, &sn1, &cs1);
        __sincosf(p1.x * 0.5f, &sn2, &cs2);
        __sincosf(p1.y * 0.5f, &sn3, &cs3);

        // r[k], k = b0*8+b1*4+b2*2+b3 (wire0 = MSB), factor = bit? sin : cos
        float r4[4];
        r4[0] = cs0 * cs1; r4[1] = cs0 * sn1; r4[2] = sn0 * cs1; r4[3] = sn0 * sn1;
        float r8[8];
        #pragma unroll
        for (int t = 0; t < 4; ++t) { r8[2 * t] = r4[t] * cs2; r8[2 * t + 1] = r4[t] * sn2; }
        float r[16];
        #pragma unroll
        for (int t = 0; t < 8; ++t) { r[2 * t] = r8[t] * cs3; r[2 * t + 1] = r8[t] * sn3; }

        // matvec: y_j = sum_k W'[j][k] * r[k]  (W' complex, r real)
        const float2* __restrict__ wrow = wp + ((c << 3) + d) * 256;
        float q[16];
        #pragma unroll
        for (int jj = 0; jj < 16; ++jj) {
            const float4* wr4 = (const float4*)(wrow + jj * 16);
            float yr = 0.f, yi = 0.f;
            #pragma unroll
            for (int kk = 0; kk < 8; ++kk) {
                float4 wv = wr4[kk];
                yr = fmaf(wv.x, r[2 * kk], yr);
                yi = fmaf(wv.y, r[2 * kk], yi);
                yr = fmaf(wv.z, r[2 * kk + 1], yr);
                yi = fmaf(wv.w, r[2 * kk + 1], yi);
            }
            q[jj] = yr * yr + yi * yi;
        }

        // marginals via partial-sum butterfly
        float s1[8], t3 = 0.f;
        #pragma unroll
        for (int a = 0; a < 8; ++a) {
            s1[a] = q[2 * a] + q[2 * a + 1];
            t3 += q[2 * a] - q[2 * a + 1];
        }
        float s2[4], t2 = 0.f;
        #pragma unroll
        for (int a = 0; a < 4; ++a) {
            s2[a] = s1[2 * a] + s1[2 * a + 1];
            t2 += s1[2 * a] - s1[2 * a + 1];
        }
        float s30 = s2[0] + s2[1], s31 = s2[2] + s2[3];
        float t1 = (s2[0] - s2[1]) + (s2[2] - s2[3]);
        float t0 = s30 - s31;

        outacc0 += acos_fast(fminf(fmaxf(t0, -1.f), 1.f));
        outacc1 += acos_fast(fminf(fmaxf(t1, -1.f), 1.f));
        outacc2 += acos_fast(fminf(fmaxf(t2, -1.f), 1.f));
        outacc3 += acos_fast(fminf(fmaxf(t3, -1.f), 1.f));
    }

    if (chalf == 1) {
        lds[0][tm] = outacc0;
        lds[1][tm] = outacc1;
        lds[2][tm] = outacc2;
        lds[3][tm] = outacc3;
    }
    __syncthreads();
    if (chalf == 0) {
        // out[b][d*4+w][ix][iy], channel stride 1024
        float* ob = out + (((b * 32) + (d << 2)) * 32 + ix) * 32 + iy;
        ob[0]    = outacc0 + lds[0][tm];
        ob[1024] = outacc1 + lds[1][tm];
        ob[2048] = outacc2 + lds[2][tm];
        ob[3072] = outacc3 + lds[3][tm];
    }
}

extern "C" void kernel_launch(void* const* d_in, const int* in_sizes, int n_in,
                              void* d_out, int out_size, void* d_ws, size_t ws_size,
                              hipStream_t stream) {
    const float* x = (const float*)d_in[0];
    const float* params = (const float*)d_in[1];
    float* out = (float*)d_out;
    float2* wp = (float2*)d_ws;   // 32 * 256 * 8 bytes = 64 KiB

    expm_kernel<<<NMAT, 256, 0, stream>>>(params, wp);
    qconv_kernel<<<8 * 128, 512, 0, stream>>>(x, wp, out);
}

// Round 4
// 46.317 us; speedup vs baseline: 1.6477x; 1.6477x over previous
//
#include <hip/hip_runtime.h>
#include <math.h>

// QConv2d: x (32,4,64,64) f32, params (4,8,16,16) f32 -> out (32,32,32,32) f32
// B=32 C=4 H=W=64, KH=KW=2 stride 2 -> px=py=32, NW=4, DIM=16, D=8, M=32768

#define NMAT 32          // C*D matrices
#define TAYLOR_N 9

// ---------------- Kernel 1: W'[c*8+d][j][i] = expm(SH)[i][j] * (-i)^popc(i) ----
__global__ __launch_bounds__(256) void expm_kernel(const float* __restrict__ params,
                                                   float2* __restrict__ wp) {
    __shared__ float2 X[256];
    __shared__ float2 P0[256];
    __shared__ float2 P1[256];
    __shared__ float red[256];
    __shared__ float srow[16];
    __shared__ int ssexp;

    const int bid = blockIdx.x;      // c*8 + d
    const int tid = threadIdx.x;
    const int i = tid >> 4, j = tid & 15;

    const float* pm = params + bid * 256;
    float pij = pm[i * 16 + j];
    float pji = pm[j * 16 + i];
    float ar = pij - pji;   // asym -> real part of SH
    float ai = pij + pji;   // sym  -> imag part of SH
    red[tid] = fabsf(ar) + fabsf(ai);
    __syncthreads();
    if (j == 0) {
        float s = 0.f;
        for (int t = 0; t < 16; ++t) s += red[i * 16 + t];
        srow[i] = s;
    }
    __syncthreads();
    if (tid == 0) {
        float mx = 0.f;
        for (int t = 0; t < 16; ++t) mx = fmaxf(mx, srow[t]);
        int se = 0;
        while (mx > 0.5f && se < 40) { mx *= 0.5f; se++; }
        ssexp = se;
    }
    __syncthreads();
    const int sexp = ssexp;
    const float scale = exp2f((float)(-sexp));
    const float xr = ar * scale, xi = ai * scale;
    X[tid] = make_float2(xr, xi);
    // P = I + X/N
    float2 p = make_float2(xr / TAYLOR_N + ((i == j) ? 1.f : 0.f), xi / TAYLOR_N);
    P0[tid] = p;
    __syncthreads();

    float2* cur = P0;
    float2* nxt = P1;
    // Horner: P = I + X*P/k for k = N-1 .. 1
    for (int k = TAYLOR_N - 1; k >= 1; --k) {
        float accr = 0.f, acci = 0.f;
        #pragma unroll
        for (int t = 0; t < 16; ++t) {
            float2 a = X[i * 16 + t];
            float2 b = cur[t * 16 + j];
            accr += a.x * b.x - a.y * b.y;
            acci += a.x * b.y + a.y * b.x;
        }
        float inv = 1.f / (float)k;
        float2 np = make_float2(accr * inv + ((i == j) ? 1.f : 0.f), acci * inv);
        __syncthreads();
        nxt[tid] = np;
        __syncthreads();
        float2* tmp = cur; cur = nxt; nxt = tmp;
    }
    // squarings
    for (int sq = 0; sq < sexp; ++sq) {
        float accr = 0.f, acci = 0.f;
        #pragma unroll
        for (int t = 0; t < 16; ++t) {
            float2 a = cur[i * 16 + t];
            float2 b = cur[t * 16 + j];
            accr += a.x * b.x - a.y * b.y;
            acci += a.x * b.y + a.y * b.x;
        }
        __syncthreads();
        nxt[tid] = make_float2(accr, acci);
        __syncthreads();
        float2* tmp = cur; cur = nxt; nxt = tmp;
    }
    // E[i][j] = U[i][j]; store W'[j][i] = U[i][j]*(-i)^popc(i)
    float2 e = cur[tid];
    int pc = __popc(i) & 3;
    float2 o;
    if (pc == 0)      o = make_float2( e.x,  e.y);
    else if (pc == 1) o = make_float2( e.y, -e.x);
    else if (pc == 2) o = make_float2(-e.x, -e.y);
    else              o = make_float2(-e.y,  e.x);
    wp[(bid * 16 + j) * 16 + i] = o;
}

// Fast acos: A&S 4.4.45, |abs err| <= 6.8e-5 over [-1,1]
__device__ __forceinline__ float acos_fast(float t) {
    float ax = fabsf(t);
    float p = fmaf(ax, -0.0187293f, 0.0742610f);
    p = fmaf(ax, p, -0.2121144f);
    p = fmaf(ax, p, 1.5707288f);
    float f = sqrtf(1.0f - ax) * p;
    return (t >= 0.f) ? f : (3.14159265358979f - f);
}

// ---------------- Kernel 2: main compute ------------------------------------
// grid = 8(d) * 128(mb) blocks, 512 threads.
// Waves [0,4): channels {0,1}; waves [4,8): channels {2,3} (chalf forced to
// SGPR via readfirstlane so W' loads scalarize -> s_load, VALU stays free).
// Half 1 deposits partials in LDS; half 0 adds and stores. No atomics/memset.
__global__ __launch_bounds__(512) void qconv_kernel(const float* __restrict__ x,
                                                    const float2* __restrict__ wp,
                                                    float* __restrict__ out) {
    __shared__ float lds[4][256];

    const int bidx = blockIdx.x;
    const int d = bidx >> 7;          // uniform per block
    const int mb = bidx & 127;
    const int tid = threadIdx.x;
    // bit 8 of tid is constant within a 64-lane wave -> readfirstlane is exact,
    // and guarantees the compiler an SGPR value (keeps W' loads scalar).
    const int chalf = __builtin_amdgcn_readfirstlane(tid >> 8);
    const int tm = tid & 255;
    const int m = mb * 256 + tm;
    const int b = m >> 10;
    const int rem = m & 1023;
    const int ix = rem >> 5;
    const int iy = rem & 31;

    float outacc0 = 0.f, outacc1 = 0.f, outacc2 = 0.f, outacc3 = 0.f;

    #pragma unroll
    for (int cc = 0; cc < 2; ++cc) {
        const int c = chalf * 2 + cc;   // scalar
        const float* xc = x + (((b << 2) + c) * 64 + 2 * ix) * 64 + 2 * iy;
        float2 p0 = *(const float2*)xc;          // theta0, theta1 (kh=0)
        float2 p1 = *(const float2*)(xc + 64);   // theta2, theta3 (kh=1)

        float sn0, cs0, sn1, cs1, sn2, cs2, sn3, cs3;
        __sincosf(p0.x * 0.5f, &sn0, &cs0);
        __sincosf(p0.y * 0.5f, &sn1, &cs1);
        __sincosf(p1.x * 0.5f, &sn2, &cs2);
        __sincosf(p1.y * 0.5f, &sn3, &cs3);

        // r[k], k = b0*8+b1*4+b2*2+b3 (wire0 = MSB), factor = bit? sin : cos
        float r4[4];
        r4[0] = cs0 * cs1; r4[1] = cs0 * sn1; r4[2] = sn0 * cs1; r4[3] = sn0 * sn1;
        float r8[8];
        #pragma unroll
        for (int t = 0; t < 4; ++t) { r8[2 * t] = r4[t] * cs2; r8[2 * t + 1] = r4[t] * sn2; }
        float r[16];
        #pragma unroll
        for (int t = 0; t < 8; ++t) { r[2 * t] = r8[t] * cs3; r[2 * t + 1] = r8[t] * sn3; }

        // matvec: y_j = sum_k W'[j][k] * r[k]  (W' complex, r real)
        const float2* __restrict__ wrow = wp + ((c << 3) + d) * 256;  // scalar ptr
        float q[16];
        #pragma unroll
        for (int jj = 0; jj < 16; ++jj) {
            const float4* wr4 = (const float4*)(wrow + jj * 16);
            float yr = 0.f, yi = 0.f;
            #pragma unroll
            for (int kk = 0; kk < 8; ++kk) {
                float4 wv = wr4[kk];
                yr = fmaf(wv.x, r[2 * kk], yr);
                yi = fmaf(wv.y, r[2 * kk], yi);
                yr = fmaf(wv.z, r[2 * kk + 1], yr);
                yi = fmaf(wv.w, r[2 * kk + 1], yi);
            }
            q[jj] = yr * yr + yi * yi;
        }

        // marginals via partial-sum butterfly
        float s1[8], t3 = 0.f;
        #pragma unroll
        for (int a = 0; a < 8; ++a) {
            s1[a] = q[2 * a] + q[2 * a + 1];
            t3 += q[2 * a] - q[2 * a + 1];
        }
        float s2[4], t2 = 0.f;
        #pragma unroll
        for (int a = 0; a < 4; ++a) {
            s2[a] = s1[2 * a] + s1[2 * a + 1];
            t2 += s1[2 * a] - s1[2 * a + 1];
        }
        float s30 = s2[0] + s2[1], s31 = s2[2] + s2[3];
        float t1 = (s2[0] - s2[1]) + (s2[2] - s2[3]);
        float t0 = s30 - s31;

        outacc0 += acos_fast(fminf(fmaxf(t0, -1.f), 1.f));
        outacc1 += acos_fast(fminf(fmaxf(t1, -1.f), 1.f));
        outacc2 += acos_fast(fminf(fmaxf(t2, -1.f), 1.f));
        outacc3 += acos_fast(fminf(fmaxf(t3, -1.f), 1.f));
    }

    if (chalf == 1) {
        lds[0][tm] = outacc0;
        lds[1][tm] = outacc1;
        lds[2][tm] = outacc2;
        lds[3][tm] = outacc3;
    }
    __syncthreads();
    if (chalf == 0) {
        // out[b][d*4+w][ix][iy], channel stride 1024
        float* ob = out + (((b * 32) + (d << 2)) * 32 + ix) * 32 + iy;
        ob[0]    = outacc0 + lds[0][tm];
        ob[1024] = outacc1 + lds[1][tm];
        ob[2048] = outacc2 + lds[2][tm];
        ob[3072] = outacc3 + lds[3][tm];
    }
}

extern "C" void kernel_launch(void* const* d_in, const int* in_sizes, int n_in,
                              void* d_out, int out_size, void* d_ws, size_t ws_size,
                              hipStream_t stream) {
    const float* x = (const float*)d_in[0];
    const float* params = (const float*)d_in[1];
    float* out = (float*)d_out;
    float2* wp = (float2*)d_ws;   // 32 * 256 * 8 bytes = 64 KiB

    expm_kernel<<<NMAT, 256, 0, stream>>>(params, wp);
    qconv_kernel<<<8 * 128, 512, 0, stream>>>(x, wp, out);
}